// Round 1
// baseline (797.190 us; speedup 1.0000x reference)
//
#include <hip/hip_runtime.h>
#include <math.h>

#define PI2 6.283185307179586f

// Problem constants: B=32, H=W=64, C1=32, C2=64, K=5, FC1=512, HW=4096, FLAT=262144

// ---------- k1: a1[i,hw] = |fft2(pad(w1))[i,hw]|  (32 x 4096) ----------
__global__ void k1_a1(const float* __restrict__ w1r, const float* __restrict__ w1i,
                      float* __restrict__ a1) {
    int idx = blockIdx.x * 256 + threadIdx.x;   // i*4096 + hw
    int i  = idx >> 12;
    int hw = idx & 4095;
    int u = hw >> 6, v = hw & 63;
    const float* wr = w1r + i * 25;
    const float* wi = w1i + i * 25;
    float re = 0.f, im = 0.f;
    #pragma unroll
    for (int p = 0; p < 5; ++p) {
        #pragma unroll
        for (int q = 0; q < 5; ++q) {
            float s, c;
            sincosf(-(PI2 / 64.f) * (float)((u * p + v * q) & 63), &s, &c);
            float ar = wr[p * 5 + q], ai = wi[p * 5 + q];
            re += ar * c - ai * s;
            im += ar * s + ai * c;
        }
    }
    a1[idx] = sqrtf(re * re + im * im);
}

// ---------- k2a: G[o,i,p,v] = sum_q w2[o,i,p,q] * e^{-2pi i (v q)/64}  (complex) ----------
__global__ void k2a_G(const float* __restrict__ w2r, const float* __restrict__ w2i,
                      float* __restrict__ G) {
    int idx = blockIdx.x * 256 + threadIdx.x;   // ((oi*5)+p)*64 + v ; oi = o*32+i
    int v  = idx & 63;
    int p  = (idx >> 6) % 5;
    int oi = idx / 320;
    const float* wr = w2r + oi * 25 + p * 5;
    const float* wi = w2i + oi * 25 + p * 5;
    float re = 0.f, im = 0.f;
    #pragma unroll
    for (int q = 0; q < 5; ++q) {
        float s, c;
        sincosf(-(PI2 / 64.f) * (float)((v * q) & 63), &s, &c);
        re += wr[q] * c - wi[q] * s;
        im += wr[q] * s + wi[q] * c;
    }
    G[2 * idx]     = re;
    G[2 * idx + 1] = im;
}

// ---------- k2b: t[o,hw] = | sum_i a1[i,hw] * (sum_p e_u[p] * G[o,i,p,v]) | ----------
// One block per (o, u-group of 16). G[o] slice staged in LDS in two 40KB halves.
__global__ void k2b_t(const float* __restrict__ G, const float* __restrict__ a1,
                      float* __restrict__ t) {
    __shared__ float Gs[10240];                 // 16 i's worth: 16*5*64*2 floats = 40 KB
    int o  = blockIdx.x >> 2;
    int ug = blockIdx.x & 3;
    const float* Go = G + o * 20480;            // full o-slice: 32*5*64*2 floats
    float re[4] = {0.f, 0.f, 0.f, 0.f};
    float im[4] = {0.f, 0.f, 0.f, 0.f};
    for (int half = 0; half < 2; ++half) {
        __syncthreads();
        for (int jj = threadIdx.x; jj < 10240; jj += 256)
            Gs[jj] = Go[half * 10240 + jj];
        __syncthreads();
        #pragma unroll
        for (int jt = 0; jt < 4; ++jt) {
            int j = jt * 256 + threadIdx.x;     // 0..1023 within this block's uv range
            int u = ug * 16 + (j >> 6);
            int v = j & 63;
            float cu[5], su[5];
            #pragma unroll
            for (int p = 0; p < 5; ++p)
                sincosf(-(PI2 / 64.f) * (float)((u * p) & 63), &su[p], &cu[p]);
            #pragma unroll 4
            for (int i = 0; i < 16; ++i) {
                float a = a1[(half * 16 + i) * 4096 + u * 64 + v];
                float sr = 0.f, si = 0.f;
                #pragma unroll
                for (int p = 0; p < 5; ++p) {
                    float gr = Gs[2 * ((i * 5 + p) * 64 + v)];
                    float gi = Gs[2 * ((i * 5 + p) * 64 + v) + 1];
                    sr += gr * cu[p] - gi * su[p];
                    si += gr * su[p] + gi * cu[p];
                }
                re[jt] += a * sr;
                im[jt] += a * si;
            }
        }
    }
    #pragma unroll
    for (int jt = 0; jt < 4; ++jt) {
        int j = jt * 256 + threadIdx.x;
        int u = ug * 16 + (j >> 6);
        int v = j & 63;
        t[o * 4096 + u * 64 + v] = sqrtf(re[jt] * re[jt] + im[jt] * im[jt]);
    }
}

// ---------- k3: THE memory-bound pass. Streams fc1_w (512 MB) once. ----------
// W1eff[f,hw] = sum_o t[o,hw]*fc1_w[f,o*4096+hw]  kept in registers (float4),
// immediately contracted with |x[b,hw]| and reduced into y1[b,f] (atomic).
__global__ __launch_bounds__(256) void k3_y1(
        const float* __restrict__ fc1_w, const float* __restrict__ t,
        const float* __restrict__ x, float* __restrict__ y1) {
    int f  = blockIdx.x >> 2;
    int hb = blockIdx.x & 3;
    int hw = hb * 1024 + threadIdx.x * 4;
    const float4* wrow = (const float4*)(fc1_w + (size_t)f * 262144);
    float4 acc = make_float4(0.f, 0.f, 0.f, 0.f);
    #pragma unroll 4
    for (int o = 0; o < 64; ++o) {
        float4 wv = wrow[(o * 4096 + hw) >> 2];
        float4 tv = *(const float4*)(t + o * 4096 + hw);
        acc.x += tv.x * wv.x;
        acc.y += tv.y * wv.y;
        acc.z += tv.z * wv.z;
        acc.w += tv.w * wv.w;
    }
    // contract with |x| for all 32 batches
    float part[32];
    #pragma unroll
    for (int b = 0; b < 32; ++b) {
        float4 xv = *(const float4*)(x + b * 4096 + hw);
        part[b] = acc.x * fabsf(xv.x) + acc.y * fabsf(xv.y)
                + acc.z * fabsf(xv.z) + acc.w * fabsf(xv.w);
    }
    // wave64 butterfly reduce each of the 32 partials
    #pragma unroll
    for (int b = 0; b < 32; ++b) {
        #pragma unroll
        for (int m = 32; m >= 1; m >>= 1)
            part[b] += __shfl_xor(part[b], m, 64);
    }
    __shared__ float red[4][32];
    int wave = threadIdx.x >> 6;
    int lane = threadIdx.x & 63;
    if (lane == 0) {
        #pragma unroll
        for (int b = 0; b < 32; ++b) red[wave][b] = part[b];
    }
    __syncthreads();
    if (threadIdx.x < 32) {
        float s = red[0][threadIdx.x] + red[1][threadIdx.x]
                + red[2][threadIdx.x] + red[3][threadIdx.x];
        atomicAdd(&y1[threadIdx.x * 512 + f], s);
    }
}

// ---------- k4: out[b,c] = sum_f fc2_w[c,f]*(y1[b,f]+fc1_b[f]) + fc2_b[c] ----------
__global__ void k4_out(const float* __restrict__ y1, const float* __restrict__ fc1_b,
                       const float* __restrict__ fc2_w, const float* __restrict__ fc2_b,
                       float* __restrict__ out) {
    int tid = threadIdx.x;
    if (tid >= 320) return;
    int b = tid / 10, c = tid % 10;
    float acc = fc2_b[c];
    for (int f = 0; f < 512; ++f)
        acc += fc2_w[c * 512 + f] * (y1[b * 512 + f] + fc1_b[f]);
    out[b * 10 + c] = acc;
}

extern "C" void kernel_launch(void* const* d_in, const int* in_sizes, int n_in,
                              void* d_out, int out_size, void* d_ws, size_t ws_size,
                              hipStream_t stream) {
    const float* x    = (const float*)d_in[0];
    const float* w1r  = (const float*)d_in[1];
    const float* w1i  = (const float*)d_in[2];
    const float* w2r  = (const float*)d_in[3];
    const float* w2i  = (const float*)d_in[4];
    const float* fc1w = (const float*)d_in[5];
    const float* fc1b = (const float*)d_in[6];
    const float* fc2w = (const float*)d_in[7];
    const float* fc2b = (const float*)d_in[8];
    float* out = (float*)d_out;

    // workspace layout (floats): a1[131072] | G[1310720] | t[262144] | y1[16384]
    float* a1 = (float*)d_ws;
    float* G  = a1 + 131072;
    float* t  = G + 1310720;
    float* y1 = t + 262144;

    hipMemsetAsync(y1, 0, 16384 * sizeof(float), stream);            // ws is poisoned 0xAA
    k1_a1<<<512, 256, 0, stream>>>(w1r, w1i, a1);                    // 32*4096 elems
    k2a_G<<<2560, 256, 0, stream>>>(w2r, w2i, G);                    // 64*32*5*64 elems
    k2b_t<<<256, 256, 0, stream>>>(G, a1, t);                        // (o, u-group) blocks
    k3_y1<<<2048, 256, 0, stream>>>(fc1w, t, x, y1);                 // 512 f x 4 hw-blocks
    k4_out<<<1, 320, 0, stream>>>(y1, fc1b, fc2w, fc2b, out);
}

// Round 3
// 768.006 us; speedup vs baseline: 1.0380x; 1.0380x over previous
//
#include <hip/hip_runtime.h>
#include <math.h>

#define PI2 6.283185307179586f

typedef float floatx4 __attribute__((ext_vector_type(4)));

// Problem constants: B=32, H=W=64, C1=32, C2=64, K=5, FC1=512, HW=4096, FLAT=262144
// Algebra: y = fc2( fc1( flat(h2) ) ), h2[b,o,hw] = |x[b,hw]| * t[o,hw],
//          t[o,hw] = |sum_i a1[i,hw] * kf2[o,i,hw]|, a1[i,hw] = |kf1[i,hw]|.
// So y1[b,f] = sum_hw |x[b,hw]| * W1eff[f,hw],  W1eff[f,hw] = sum_o t[o,hw]*fc1_w[f,o*4096+hw].
// Only mandatory HBM traffic: fc1_w, 512 MB, read exactly once (k3).

// ---------- kA: fused (k1) a1[i,hw]=|fft2(pad(w1))| and (k2a) row-DFT of w2 ----------
__global__ void kA_small(const float* __restrict__ w1r, const float* __restrict__ w1i,
                         const float* __restrict__ w2r, const float* __restrict__ w2i,
                         float* __restrict__ a1, float* __restrict__ G_re,
                         float* __restrict__ G_im) {
    if (blockIdx.x < 512) {
        // k1: a1 (32 x 4096)
        int idx = blockIdx.x * 256 + threadIdx.x;   // i*4096 + hw
        int i  = idx >> 12;
        int hw = idx & 4095;
        int u = hw >> 6, v = hw & 63;
        const float* wr = w1r + i * 25;
        const float* wi = w1i + i * 25;
        float re = 0.f, im = 0.f;
        #pragma unroll
        for (int p = 0; p < 5; ++p) {
            #pragma unroll
            for (int q = 0; q < 5; ++q) {
                float s, c;
                sincosf(-(PI2 / 64.f) * (float)((u * p + v * q) & 63), &s, &c);
                float ar = wr[p * 5 + q], ai = wi[p * 5 + q];
                re += ar * c - ai * s;
                im += ar * s + ai * c;
            }
        }
        a1[idx] = sqrtf(re * re + im * im);
    } else {
        // k2a: G[o,i,p,v] = sum_q w2[o,i,p,q] * e^{-2pi i (v q)/64}, de-interleaved planes
        int idx = (blockIdx.x - 512) * 256 + threadIdx.x;  // ((oi*5)+p)*64 + v
        int v  = idx & 63;
        int p  = (idx >> 6) % 5;
        int oi = idx / 320;
        const float* wr = w2r + oi * 25 + p * 5;
        const float* wi = w2i + oi * 25 + p * 5;
        float re = 0.f, im = 0.f;
        #pragma unroll
        for (int q = 0; q < 5; ++q) {
            float s, c;
            sincosf(-(PI2 / 64.f) * (float)((v * q) & 63), &s, &c);
            re += wr[q] * c - wi[q] * s;
            im += wr[q] * s + wi[q] * c;
        }
        G_re[idx] = re;
        G_im[idx] = im;
    }
}

// ---------- k2b: t[o,hw] = | sum_i a1[i,hw] * (sum_p e_u[p] * G[o,i,p,v]) | ----------
// One block per (o, u-group of 16). G[o] slice staged in LDS, de-interleaved planes
// so inner reads are stride-1 (v contiguous -> 2 lanes/bank, conflict-free).
__global__ void k2b_t(const float* __restrict__ G_re, const float* __restrict__ G_im,
                      const float* __restrict__ a1, float* __restrict__ t) {
    __shared__ float Gsr[5120];   // 16 i's: 16*5*64 floats (re)
    __shared__ float Gsi[5120];   // (im)
    int o  = blockIdx.x >> 2;
    int ug = blockIdx.x & 3;
    float re[4] = {0.f, 0.f, 0.f, 0.f};
    float im[4] = {0.f, 0.f, 0.f, 0.f};
    for (int half = 0; half < 2; ++half) {
        __syncthreads();
        for (int jj = threadIdx.x; jj < 5120; jj += 256) {
            Gsr[jj] = G_re[o * 10240 + half * 5120 + jj];
            Gsi[jj] = G_im[o * 10240 + half * 5120 + jj];
        }
        __syncthreads();
        #pragma unroll
        for (int jt = 0; jt < 4; ++jt) {
            int j = jt * 256 + threadIdx.x;     // 0..1023 within this block's uv range
            int u = ug * 16 + (j >> 6);
            int v = j & 63;
            float cu[5], su[5];
            #pragma unroll
            for (int p = 0; p < 5; ++p)
                sincosf(-(PI2 / 64.f) * (float)((u * p) & 63), &su[p], &cu[p]);
            #pragma unroll 4
            for (int i = 0; i < 16; ++i) {
                float a = a1[(half * 16 + i) * 4096 + u * 64 + v];
                float sr = 0.f, si = 0.f;
                #pragma unroll
                for (int p = 0; p < 5; ++p) {
                    float gr = Gsr[(i * 5 + p) * 64 + v];
                    float gi = Gsi[(i * 5 + p) * 64 + v];
                    sr += gr * cu[p] - gi * su[p];
                    si += gr * su[p] + gi * cu[p];
                }
                re[jt] += a * sr;
                im[jt] += a * si;
            }
        }
    }
    #pragma unroll
    for (int jt = 0; jt < 4; ++jt) {
        int j = jt * 256 + threadIdx.x;
        int u = ug * 16 + (j >> 6);
        int v = j & 63;
        t[o * 4096 + u * 64 + v] = sqrtf(re[jt] * re[jt] + im[jt] * im[jt]);
    }
}

// ---------- k3: THE memory-bound pass. Streams fc1_w (512 MB) exactly once. ----------
// 2 FC1 rows per block; W1eff fragments live in registers; nontemporal on the
// 512 MB stream so L2 keeps t (1 MB) and x (0.5 MB) resident.
__global__ __launch_bounds__(256) void k3_y1(
        const float* __restrict__ fc1_w, const float* __restrict__ t,
        const float* __restrict__ x, float* __restrict__ y1) {
    int f0 = (blockIdx.x >> 2) * 2;
    int hb = blockIdx.x & 3;
    int hw = hb * 1024 + threadIdx.x * 4;
    const floatx4* w0 = (const floatx4*)(fc1_w + (size_t)f0 * 262144);
    const floatx4* w1 = (const floatx4*)(fc1_w + (size_t)(f0 + 1) * 262144);
    floatx4 acc0 = (floatx4)(0.f);
    floatx4 acc1 = (floatx4)(0.f);
    #pragma unroll 8
    for (int o = 0; o < 64; ++o) {
        int e = (o * 4096 + hw) >> 2;
        floatx4 tv = *(const floatx4*)(t + o * 4096 + hw);
        floatx4 wa = __builtin_nontemporal_load(w0 + e);
        floatx4 wb = __builtin_nontemporal_load(w1 + e);
        acc0 += tv * wa;
        acc1 += tv * wb;
    }
    __shared__ float red[4][32][2];
    int wave = threadIdx.x >> 6;
    int lane = threadIdx.x & 63;
    for (int b = 0; b < 32; ++b) {
        floatx4 xv = *(const floatx4*)(x + b * 4096 + hw);
        float ax = fabsf(xv.x), ay = fabsf(xv.y), az = fabsf(xv.z), aw = fabsf(xv.w);
        float p0 = acc0.x * ax + acc0.y * ay + acc0.z * az + acc0.w * aw;
        float p1 = acc1.x * ax + acc1.y * ay + acc1.z * az + acc1.w * aw;
        #pragma unroll
        for (int m = 32; m >= 1; m >>= 1) {
            p0 += __shfl_xor(p0, m, 64);
            p1 += __shfl_xor(p1, m, 64);
        }
        if (lane == 0) { red[wave][b][0] = p0; red[wave][b][1] = p1; }
    }
    __syncthreads();
    if (threadIdx.x < 64) {
        int b = threadIdx.x >> 1, ff = threadIdx.x & 1;
        float s = red[0][b][ff] + red[1][b][ff] + red[2][b][ff] + red[3][b][ff];
        atomicAdd(&y1[b * 512 + f0 + ff], s);
    }
}

// ---------- k4: out[b,c] = sum_f fc2_w[c,f]*(y1[b,f]+fc1_b[f]) + fc2_b[c] ----------
__global__ void k4_out(const float* __restrict__ y1, const float* __restrict__ fc1_b,
                       const float* __restrict__ fc2_w, const float* __restrict__ fc2_b,
                       float* __restrict__ out) {
    int tid = threadIdx.x;
    if (tid >= 320) return;
    int b = tid / 10, c = tid % 10;
    float acc = fc2_b[c];
    for (int f = 0; f < 512; ++f)
        acc += fc2_w[c * 512 + f] * (y1[b * 512 + f] + fc1_b[f]);
    out[b * 10 + c] = acc;
}

extern "C" void kernel_launch(void* const* d_in, const int* in_sizes, int n_in,
                              void* d_out, int out_size, void* d_ws, size_t ws_size,
                              hipStream_t stream) {
    const float* x    = (const float*)d_in[0];
    const float* w1r  = (const float*)d_in[1];
    const float* w1i  = (const float*)d_in[2];
    const float* w2r  = (const float*)d_in[3];
    const float* w2i  = (const float*)d_in[4];
    const float* fc1w = (const float*)d_in[5];
    const float* fc1b = (const float*)d_in[6];
    const float* fc2w = (const float*)d_in[7];
    const float* fc2b = (const float*)d_in[8];
    float* out = (float*)d_out;

    // workspace (floats): a1[131072] | G_re[655360] | G_im[655360] | t[262144] | y1[16384]
    float* a1   = (float*)d_ws;
    float* G_re = a1 + 131072;
    float* G_im = G_re + 655360;
    float* t    = G_im + 655360;
    float* y1   = t + 262144;

    (void)hipMemsetAsync(y1, 0, 16384 * sizeof(float), stream);   // ws is poisoned 0xAA
    kA_small<<<3072, 256, 0, stream>>>(w1r, w1i, w2r, w2i, a1, G_re, G_im);
    k2b_t<<<256, 256, 0, stream>>>(G_re, G_im, a1, t);
    k3_y1<<<1024, 256, 0, stream>>>(fc1w, t, x, y1);        // 256 f-pairs x 4 hw-blocks
    k4_out<<<1, 320, 0, stream>>>(y1, fc1b, fc2w, fc2b, out);
}